// Round 5
// baseline (415.885 us; speedup 1.0000x reference)
//
#include <hip/hip_runtime.h>

#define T 32
#define C 2048
#define NTOT 600
#define NCLASS 20
#define NSUP 5
#define PER 30
#define NQPC 25
#define NQ 500
#define NQROWS (NQ * T)      // 16000
#define NPROWS (NCLASS * T)  // 640
#define GAMMA 0.1f
#define INVG 10.0f
#define BIG 1e10f
#define NMM (NQ * NCLASS + NQ + NCLASS)  // 10520
#define GEMM_BLKS 625
#define SYRK_BLKS 130
#define NA_ITEMS (NQROWS * 64)  // 1,024,000 (row-segments of 32 floats)
#define NB_ITEMS (NPROWS * 64)  // 40,960
#define STAGE_BLKS ((NA_ITEMS + NB_ITEMS) / 256)  // 4160

typedef short bf16x8 __attribute__((ext_vector_type(8)));
typedef float f32x4 __attribute__((ext_vector_type(4)));

__device__ __forceinline__ void gload16(const void* g, void* l) {
    __builtin_amdgcn_global_load_lds((const __attribute__((address_space(1))) void*)g,
                                     (__attribute__((address_space(3))) void*)l, 16, 0, 0);
}

__device__ __forceinline__ unsigned bf16_rne(float f) {
    unsigned u = __float_as_uint(f);
    return (u + 0x7fffu + ((u >> 16) & 1u)) >> 16;
}

// ---------------- parallel stable counting sort (1 block) ----------------
__global__ __launch_bounds__(640) void sort_kernel(const int* __restrict__ target,
                                                   int* __restrict__ order,
                                                   int* __restrict__ qsrc) {
    __shared__ int tgt[NTOT];
    __shared__ int offs[NCLASS];
    __shared__ int ordl[NTOT];
    int tid = threadIdx.x;
    if (tid < NTOT) tgt[tid] = target[tid];
    __syncthreads();
    if (tid < NCLASS) {
        int o = 0;
        for (int i = 0; i < NTOT; i++) o += (tgt[i] < tid) ? 1 : 0;
        offs[tid] = o;
    }
    __syncthreads();
    if (tid < NTOT) {
        int c = tgt[tid];
        int rank = 0;
        for (int k = 0; k < NTOT; k++) rank += (k < tid && tgt[k] == c) ? 1 : 0;
        ordl[offs[c] + rank] = tid;
    }
    __syncthreads();
    if (tid < NTOT) order[tid] = ordl[tid];
    if (tid < NQ) qsrc[tid] = ordl[(tid / NQPC) * PER + NSUP + (tid % NQPC)];
}

// ---------------- streaming staging: gather/mean + hi/lo split + norms ----------------
// Staged layout: ROW-MAJOR [row][C/8] of bf16x8 (chunk c covers cols c*8..c*8+7).
// One thread = 32 consecutive floats of one row; one wave = exactly one row.
__global__ __launch_bounds__(256) void stage_kernel(const float* __restrict__ inp,
                                                    const int* __restrict__ qsrc,
                                                    const int* __restrict__ order,
                                                    bf16x8* __restrict__ Ah,
                                                    bf16x8* __restrict__ Al,
                                                    bf16x8* __restrict__ Bh,
                                                    bf16x8* __restrict__ Bl,
                                                    float* __restrict__ x2,
                                                    float* __restrict__ y2) {
    int gid = blockIdx.x * 256 + threadIdx.x;
    int lane = threadIdx.x & 63;
    bool isA = gid < NA_ITEMS;
    int item = isA ? gid : gid - NA_ITEMS;
    int row = item >> 6, seg = item & 63;  // seg == lane
    float vals[32];
    if (isA) {
        const float* src = inp + (size_t)qsrc[row >> 5] * (T * C) + (size_t)(row & 31) * C + seg * 32;
#pragma unroll
        for (int i = 0; i < 8; i++) {
            float4 v = *(const float4*)(src + i * 4);
            vals[i * 4 + 0] = v.x; vals[i * 4 + 1] = v.y;
            vals[i * 4 + 2] = v.z; vals[i * 4 + 3] = v.w;
        }
    } else {
        int cls = row >> 5, trow = row & 31;
        const float* base = inp + (size_t)trow * C + seg * 32;
        const float* s0 = base + (size_t)order[cls * PER + 0] * (T * C);
        const float* s1 = base + (size_t)order[cls * PER + 1] * (T * C);
        const float* s2 = base + (size_t)order[cls * PER + 2] * (T * C);
        const float* s3 = base + (size_t)order[cls * PER + 3] * (T * C);
        const float* s4 = base + (size_t)order[cls * PER + 4] * (T * C);
#pragma unroll
        for (int i = 0; i < 8; i++) {
            float4 a = *(const float4*)(s0 + i * 4);
            float4 b = *(const float4*)(s1 + i * 4);
            float4 c = *(const float4*)(s2 + i * 4);
            float4 d = *(const float4*)(s3 + i * 4);
            float4 e = *(const float4*)(s4 + i * 4);
            vals[i * 4 + 0] = (a.x + b.x + c.x + d.x + e.x) * 0.2f;
            vals[i * 4 + 1] = (a.y + b.y + c.y + d.y + e.y) * 0.2f;
            vals[i * 4 + 2] = (a.z + b.z + c.z + d.z + e.z) * 0.2f;
            vals[i * 4 + 3] = (a.w + b.w + c.w + d.w + e.w) * 0.2f;
        }
    }
    float sumsq = 0.f;
    bf16x8 hv[4], lv[4];
#pragma unroll
    for (int e = 0; e < 32; e++) {
        float f = vals[e];
        sumsq += f * f;
        unsigned hb = bf16_rne(f);
        float lof = f - __uint_as_float(hb << 16);
        hv[e >> 3][e & 7] = (short)hb;
        lv[e >> 3][e & 7] = (short)bf16_rne(lof);
    }
    size_t o = (size_t)row * 256 + seg * 4;
    bf16x8* dh = (isA ? Ah : Bh) + o;
    bf16x8* dl = (isA ? Al : Bl) + o;
#pragma unroll
    for (int c = 0; c < 4; c++) { dh[c] = hv[c]; dl[c] = lv[c]; }
#pragma unroll
    for (int d = 1; d < 64; d <<= 1) sumsq += __shfl_xor(sumsq, d);
    if (lane == 0) (isA ? x2 : y2)[row] = sumsq;
}

// ---------------- merged: split-bf16 MFMA GEMM (blocks 0..624) + SYRK (625..754) ----
// Operands are row-major [row][C/8]; global_load_lds source addrs are per-lane gathers,
// LDS dest stays linear. LDS content per K-step t: index i = chunk(i>>7)*128 + row(i&127).
__global__ __launch_bounds__(256) void gemm_syrk_kernel(const bf16x8* __restrict__ Ah,
                                                        const bf16x8* __restrict__ Al,
                                                        const bf16x8* __restrict__ Bh,
                                                        const bf16x8* __restrict__ Bl,
                                                        float* __restrict__ xy,
                                                        float* __restrict__ gxx,
                                                        float* __restrict__ gyy) {
    __shared__ bf16x8 sAh[512], sAl[512], sBh[512], sBl[512];  // 32 KB
    int tid = threadIdx.x, lane = tid & 63, wid = tid >> 6;
    int o = blockIdx.x;
    if (o >= GEMM_BLKS) {
        // ---- SYRK path: one wave per 32x32 Gram matrix ----
        int ww = (o - GEMM_BLKS) * 4 + wid;
        const bf16x8* hi;
        const bf16x8* lo;
        int row0;
        float* outp;
        if (ww < NQ) {
            hi = Ah; lo = Al; row0 = ww * 32;
            outp = gxx + (size_t)ww * (T * T);
        } else {
            hi = Bh; lo = Bl; row0 = (ww - NQ) * 32;
            outp = gyy + (size_t)(ww - NQ) * (T * T);
        }
        int r = lane & 15, g = lane >> 4;
        size_t a0 = (size_t)(row0 + r) * 256 + g;       // chunk t*4+g of row row0+r
        size_t a1 = (size_t)(row0 + 16 + r) * 256 + g;
        f32x4 acc[2][2];
        f32x4 zero = {0.f, 0.f, 0.f, 0.f};
        acc[0][0] = zero; acc[0][1] = zero; acc[1][0] = zero; acc[1][1] = zero;
        for (int t = 0; t < C / 32; t++) {
            bf16x8 h0 = hi[a0], h1 = hi[a1];
            bf16x8 l0 = lo[a0], l1 = lo[a1];
            a0 += 4; a1 += 4;
            acc[0][0] = __builtin_amdgcn_mfma_f32_16x16x32_bf16(h0, h0, acc[0][0], 0, 0, 0);
            acc[0][0] = __builtin_amdgcn_mfma_f32_16x16x32_bf16(h0, l0, acc[0][0], 0, 0, 0);
            acc[0][0] = __builtin_amdgcn_mfma_f32_16x16x32_bf16(l0, h0, acc[0][0], 0, 0, 0);
            acc[0][1] = __builtin_amdgcn_mfma_f32_16x16x32_bf16(h0, h1, acc[0][1], 0, 0, 0);
            acc[0][1] = __builtin_amdgcn_mfma_f32_16x16x32_bf16(h0, l1, acc[0][1], 0, 0, 0);
            acc[0][1] = __builtin_amdgcn_mfma_f32_16x16x32_bf16(l0, h1, acc[0][1], 0, 0, 0);
            acc[1][0] = __builtin_amdgcn_mfma_f32_16x16x32_bf16(h1, h0, acc[1][0], 0, 0, 0);
            acc[1][0] = __builtin_amdgcn_mfma_f32_16x16x32_bf16(h1, l0, acc[1][0], 0, 0, 0);
            acc[1][0] = __builtin_amdgcn_mfma_f32_16x16x32_bf16(l1, h0, acc[1][0], 0, 0, 0);
            acc[1][1] = __builtin_amdgcn_mfma_f32_16x16x32_bf16(h1, h1, acc[1][1], 0, 0, 0);
            acc[1][1] = __builtin_amdgcn_mfma_f32_16x16x32_bf16(h1, l1, acc[1][1], 0, 0, 0);
            acc[1][1] = __builtin_amdgcn_mfma_f32_16x16x32_bf16(l1, h1, acc[1][1], 0, 0, 0);
        }
#pragma unroll
        for (int mi = 0; mi < 2; mi++)
#pragma unroll
            for (int ni = 0; ni < 2; ni++)
#pragma unroll
                for (int j = 0; j < 4; j++)
                    outp[(mi * 16 + g * 4 + j) * T + ni * 16 + r] = acc[mi][ni][j];
        return;
    }
    // ---- GEMM path ----
    // bijective XCD swizzle over 625 = 8*78+1
    int xcd = o & 7, slot = o >> 3;
    int v = (xcd < 1 ? xcd * 79 : 79 + (xcd - 1) * 78) + slot;
    int bm = v / 5, bn = v % 5;
    int wr = wid >> 1, wc = wid & 1;
    int m0 = bm * 128, n0 = bn * 128;
    int i0 = tid, i1 = tid + 256;
    // per-lane gather source: row-major [row][256]; chunk advances by 4 each K-step
    const bf16x8* gAh0 = Ah + (size_t)(m0 + (i0 & 127)) * 256 + (i0 >> 7);
    const bf16x8* gAh1 = Ah + (size_t)(m0 + (i1 & 127)) * 256 + (i1 >> 7);
    const bf16x8* gAl0 = Al + (size_t)(m0 + (i0 & 127)) * 256 + (i0 >> 7);
    const bf16x8* gAl1 = Al + (size_t)(m0 + (i1 & 127)) * 256 + (i1 >> 7);
    const bf16x8* gBh0 = Bh + (size_t)(n0 + (i0 & 127)) * 256 + (i0 >> 7);
    const bf16x8* gBh1 = Bh + (size_t)(n0 + (i1 & 127)) * 256 + (i1 >> 7);
    const bf16x8* gBl0 = Bl + (size_t)(n0 + (i0 & 127)) * 256 + (i0 >> 7);
    const bf16x8* gBl1 = Bl + (size_t)(n0 + (i1 & 127)) * 256 + (i1 >> 7);
    f32x4 acc[4][4];
    f32x4 zero = {0.f, 0.f, 0.f, 0.f};
#pragma unroll
    for (int mi = 0; mi < 4; mi++)
#pragma unroll
        for (int ni = 0; ni < 4; ni++) acc[mi][ni] = zero;
    int g = lane >> 4, r = lane & 15;
    int aoff = g * 128 + wr * 64 + r;
    int boff = g * 128 + wc * 64 + r;
    for (int t = 0; t < C / 32; t++) {
        gload16(gAh0, &sAh[i0]); gload16(gAh1, &sAh[i1]);
        gload16(gAl0, &sAl[i0]); gload16(gAl1, &sAl[i1]);
        gload16(gBh0, &sBh[i0]); gload16(gBh1, &sBh[i1]);
        gload16(gBl0, &sBl[i0]); gload16(gBl1, &sBl[i1]);
        gAh0 += 4; gAh1 += 4; gAl0 += 4; gAl1 += 4;
        gBh0 += 4; gBh1 += 4; gBl0 += 4; gBl1 += 4;
        __syncthreads();
        bf16x8 ah[4], al[4], bh[4], bl[4];
#pragma unroll
        for (int i = 0; i < 4; i++) {
            ah[i] = sAh[aoff + i * 16];
            al[i] = sAl[aoff + i * 16];
            bh[i] = sBh[boff + i * 16];
            bl[i] = sBl[boff + i * 16];
        }
#pragma unroll
        for (int mi = 0; mi < 4; mi++)
#pragma unroll
            for (int ni = 0; ni < 4; ni++) {
                acc[mi][ni] = __builtin_amdgcn_mfma_f32_16x16x32_bf16(ah[mi], bh[ni], acc[mi][ni], 0, 0, 0);
                acc[mi][ni] = __builtin_amdgcn_mfma_f32_16x16x32_bf16(ah[mi], bl[ni], acc[mi][ni], 0, 0, 0);
                acc[mi][ni] = __builtin_amdgcn_mfma_f32_16x16x32_bf16(al[mi], bh[ni], acc[mi][ni], 0, 0, 0);
            }
        __syncthreads();
    }
    int orow = m0 + wr * 64 + (lane >> 4) * 4;
    int ocol = n0 + wc * 64 + (lane & 15);
#pragma unroll
    for (int mi = 0; mi < 4; mi++)
#pragma unroll
        for (int ni = 0; ni < 4; ni++)
#pragma unroll
            for (int j = 0; j < 4; j++)
                xy[(size_t)(orow + mi * 16 + j) * NPROWS + ocol + ni * 16] = acc[mi][ni][j];
}

// ---------------- merged soft-DTW DP: one thread per 32x32 cost matrix ----------------
__global__ void softdtw_all_kernel(const float* __restrict__ xy, const float* __restrict__ gxx,
                                   const float* __restrict__ gyy, const float* __restrict__ x2,
                                   const float* __restrict__ y2, float* __restrict__ dxy,
                                   float* __restrict__ dxx, float* __restrict__ dyy) {
    int mm = blockIdx.x * 64 + threadIdx.x;
    if (mm >= NMM) return;
    const float* rterm;
    const float* cterm;
    const float* cptr;
    int cstride;
    float* outp;
    if (mm < NQ * NCLASS) {
        int q = mm / NCLASS, m = mm % NCLASS;
        rterm = x2 + q * T;
        cterm = y2 + m * T;
        cptr = xy + (size_t)(q * T) * NPROWS + m * T;
        cstride = NPROWS;
        outp = dxy + mm;
    } else if (mm < NQ * NCLASS + NQ) {
        int i = mm - NQ * NCLASS;
        rterm = x2 + i * T;
        cterm = rterm;
        cptr = gxx + (size_t)i * (T * T);
        cstride = T;
        outp = dxx + i;
    } else {
        int i = mm - NQ * NCLASS - NQ;
        rterm = y2 + i * T;
        cterm = rterm;
        cptr = gyy + (size_t)i * (T * T);
        cstride = T;
        outp = dyy + i;
    }
    float cj[T];
#pragma unroll
    for (int j = 0; j < T; j++) cj[j] = cterm[j];
    float Rp[T + 1];
    Rp[0] = 0.f;
#pragma unroll
    for (int j = 1; j <= T; j++) Rp[j] = BIG;
    for (int i = 0; i < T; i++) {
        float diag = Rp[0];
        Rp[0] = BIG;
        float left = BIG;
        float ai = rterm[i];
        const float4* crow4 = (const float4*)(cptr + (size_t)i * cstride);
        float cr[T];
#pragma unroll
        for (int jj = 0; jj < 8; jj++) {
            float4 v = crow4[jj];
            cr[jj * 4 + 0] = v.x; cr[jj * 4 + 1] = v.y;
            cr[jj * 4 + 2] = v.z; cr[jj * 4 + 3] = v.w;
        }
#pragma unroll
        for (int j = 0; j < T; j++) {
            float up = Rp[j + 1];
            float d = ai + cj[j] - 2.0f * cr[j];
            float mn = fminf(diag, fminf(up, left));
            float ssum = __expf((mn - diag) * INVG) + __expf((mn - up) * INVG) +
                         __expf((mn - left) * INVG);
            float rr = d + mn - GAMMA * __logf(ssum);
            diag = up;
            Rp[j + 1] = rr;
            left = rr;
        }
    }
    *outp = Rp[T];
}

// ---------------- finalize: dist, log-softmax, loss, acc ----------------
__global__ __launch_bounds__(512) void finalize_kernel(const float* __restrict__ dxy,
                                                       const float* __restrict__ dxx,
                                                       const float* __restrict__ dyy,
                                                       float* __restrict__ out) {
    __shared__ float sl[512];
    __shared__ float sa[512];
    int q = threadIdx.x;
    float bl = 0.f, fl = 0.f;
    if (q < NQ) {
        float dxxq = dxx[q];
        int cq = q / NQPC;
        float dd[NCLASS];
#pragma unroll
        for (int m = 0; m < NCLASS; m++)
            dd[m] = dxy[q * NCLASS + m] - 0.5f * (dxxq + dyy[m]);
        float best = dd[0];
        int bi = 0;
#pragma unroll
        for (int m = 1; m < NCLASS; m++) {
            if (dd[m] < best) { best = dd[m]; bi = m; }
        }
        float s = 0.f;
        float dcq = dd[0];
#pragma unroll
        for (int m = 0; m < NCLASS; m++) {
            s += __expf(best - dd[m]);
            if (m == cq) dcq = dd[m];
        }
        float lse = __logf(s) - best;
        bl = dcq + lse;
        out[2 + q] = bl;
        fl = (bi == cq) ? 1.f : 0.f;
    }
    sl[threadIdx.x] = bl;
    sa[threadIdx.x] = fl;
    __syncthreads();
    for (int off = 256; off; off >>= 1) {
        if (threadIdx.x < off) {
            sl[threadIdx.x] += sl[threadIdx.x + off];
            sa[threadIdx.x] += sa[threadIdx.x + off];
        }
        __syncthreads();
    }
    if (threadIdx.x == 0) {
        out[0] = sl[0] / (float)NQ;
        out[1] = sa[0] / (float)NQ;
    }
}

extern "C" void kernel_launch(void* const* d_in, const int* in_sizes, int n_in,
                              void* d_out, int out_size, void* d_ws, size_t ws_size,
                              hipStream_t stream) {
    const float* inp = (const float*)d_in[0];
    const int* target = (const int*)d_in[1];
    float* out = (float*)d_out;
    char* ws = (char*)d_ws;

    size_t off = 0;
    auto carve = [&](size_t bytes) {
        void* p = ws + off;
        off = (off + bytes + 255) & ~(size_t)255;
        return p;
    };
    int* order = (int*)carve(NTOT * sizeof(int));
    int* qsrc = (int*)carve(NQ * sizeof(int));
    float* x2 = (float*)carve((size_t)NQROWS * sizeof(float));
    float* y2 = (float*)carve((size_t)NPROWS * sizeof(float));
    float* xy = (float*)carve((size_t)NQROWS * NPROWS * sizeof(float));  // 41 MB
    float* gxx = (float*)carve((size_t)NQ * T * T * sizeof(float));
    float* gyy = (float*)carve((size_t)NCLASS * T * T * sizeof(float));
    float* dxy = (float*)carve((size_t)NQ * NCLASS * sizeof(float));
    float* dxx = (float*)carve((size_t)NQ * sizeof(float));
    float* dyy = (float*)carve((size_t)NCLASS * sizeof(float));
    bf16x8* Ah = (bf16x8*)carve((size_t)NQROWS * 256 * 16);  // 65.5 MB row-major
    bf16x8* Al = (bf16x8*)carve((size_t)NQROWS * 256 * 16);
    bf16x8* Bh = (bf16x8*)carve((size_t)NPROWS * 256 * 16);  // 2.6 MB
    bf16x8* Bl = (bf16x8*)carve((size_t)NPROWS * 256 * 16);
    (void)ws_size;

    sort_kernel<<<1, 640, 0, stream>>>(target, order, qsrc);
    stage_kernel<<<STAGE_BLKS, 256, 0, stream>>>(inp, qsrc, order, Ah, Al, Bh, Bl, x2, y2);
    gemm_syrk_kernel<<<GEMM_BLKS + SYRK_BLKS, 256, 0, stream>>>(Ah, Al, Bh, Bl, xy, gxx, gyy);
    softdtw_all_kernel<<<(NMM + 63) / 64, 64, 0, stream>>>(xy, gxx, gyy, x2, y2, dxy, dxx, dyy);
    finalize_kernel<<<1, 512, 0, stream>>>(dxy, dxx, dyy, out);
}

// Round 6
// 308.924 us; speedup vs baseline: 1.3462x; 1.3462x over previous
//
#include <hip/hip_runtime.h>

#define T 32
#define C 2048
#define NTOT 600
#define NCLASS 20
#define NSUP 5
#define PER 30
#define NQPC 25
#define NQ 500
#define NQROWS (NQ * T)      // 16000
#define NPROWS (NCLASS * T)  // 640
#define GAMMA 0.1f
#define INVG 10.0f
#define BIG 1e10f
#define NMM (NQ * NCLASS + NQ + NCLASS)  // 10520
#define GEMM_BLKS 625
#define SYRK_BLKS 130
#define STAGE_BLKS_A 2000  // (16000/16 rows) x 2 halves
#define STAGE_BLKS_B 80    // (640/16) x 2

typedef short bf16x8 __attribute__((ext_vector_type(8)));
typedef float f32x4 __attribute__((ext_vector_type(4)));

__device__ __forceinline__ void gload16(const void* g, void* l) {
    __builtin_amdgcn_global_load_lds((const __attribute__((address_space(1))) void*)g,
                                     (__attribute__((address_space(3))) void*)l, 16, 0, 0);
}

__device__ __forceinline__ unsigned bf16_rne(float f) {
    unsigned u = __float_as_uint(f);
    return (u + 0x7fffu + ((u >> 16) & 1u)) >> 16;
}

// ---------------- parallel stable counting sort (1 block) ----------------
__global__ __launch_bounds__(640) void sort_kernel(const int* __restrict__ target,
                                                   int* __restrict__ order,
                                                   int* __restrict__ qsrc) {
    __shared__ int tgt[NTOT];
    __shared__ int offs[NCLASS];
    __shared__ int ordl[NTOT];
    int tid = threadIdx.x;
    if (tid < NTOT) tgt[tid] = target[tid];
    __syncthreads();
    if (tid < NCLASS) {
        int o = 0;
        for (int i = 0; i < NTOT; i++) o += (tgt[i] < tid) ? 1 : 0;
        offs[tid] = o;
    }
    __syncthreads();
    if (tid < NTOT) {
        int c = tgt[tid];
        int rank = 0;
        for (int k = 0; k < NTOT; k++) rank += (k < tid && tgt[k] == c) ? 1 : 0;
        ordl[offs[c] + rank] = tid;
    }
    __syncthreads();
    if (tid < NTOT) order[tid] = ordl[tid];
    if (tid < NQ) qsrc[tid] = ordl[(tid / NQPC) * PER + NSUP + (tid % NQPC)];
}

// ---------------- streaming staging: gather/mean + hi/lo split ----------------
// Output layout: CHUNK-MAJOR dst[chunk*nrows + row] (bf16x8 = cols chunk*8..+8).
// Block = 512 threads = 16 rows x 1024 cols (one half-row). Thread = 32 floats.
// row = tid&15 -> per-chunk global writes are 256B-contiguous runs. No LDS, no barriers.
__global__ __launch_bounds__(512) void stage_kernel(const float* __restrict__ inp,
                                                    const int* __restrict__ qsrc,
                                                    const int* __restrict__ order,
                                                    bf16x8* __restrict__ Ah,
                                                    bf16x8* __restrict__ Al,
                                                    bf16x8* __restrict__ Bh,
                                                    bf16x8* __restrict__ Bl) {
    int bid = blockIdx.x;
    int tid = threadIdx.x;
    int row = tid & 15, seg = tid >> 4;  // seg 0..31
    bool isA = bid < STAGE_BLKS_A;
    int b = isA ? bid : bid - STAGE_BLKS_A;
    int rowblk = b >> 1, half = b & 1;
    int row0 = rowblk * 16;
    int rowg = row0 + row;
    int col0 = half * 1024 + seg * 32;
    int nrows = isA ? NQROWS : NPROWS;
    bf16x8* dh = isA ? Ah : Bh;
    bf16x8* dl = isA ? Al : Bl;
    float vals[32];
    if (isA) {
        const float* src = inp + (size_t)qsrc[rowg >> 5] * (T * C) + (size_t)(rowg & 31) * C + col0;
#pragma unroll
        for (int i = 0; i < 8; i++) {
            float4 v = *(const float4*)(src + i * 4);
            vals[i * 4 + 0] = v.x; vals[i * 4 + 1] = v.y;
            vals[i * 4 + 2] = v.z; vals[i * 4 + 3] = v.w;
        }
    } else {
        int cls = rowg >> 5, trow = rowg & 31;
        const float* base = inp + (size_t)trow * C + col0;
        const float* s0 = base + (size_t)order[cls * PER + 0] * (T * C);
        const float* s1 = base + (size_t)order[cls * PER + 1] * (T * C);
        const float* s2 = base + (size_t)order[cls * PER + 2] * (T * C);
        const float* s3 = base + (size_t)order[cls * PER + 3] * (T * C);
        const float* s4 = base + (size_t)order[cls * PER + 4] * (T * C);
#pragma unroll
        for (int i = 0; i < 8; i++) {
            float4 a = *(const float4*)(s0 + i * 4);
            float4 b4 = *(const float4*)(s1 + i * 4);
            float4 c = *(const float4*)(s2 + i * 4);
            float4 d = *(const float4*)(s3 + i * 4);
            float4 e = *(const float4*)(s4 + i * 4);
            vals[i * 4 + 0] = (a.x + b4.x + c.x + d.x + e.x) * 0.2f;
            vals[i * 4 + 1] = (a.y + b4.y + c.y + d.y + e.y) * 0.2f;
            vals[i * 4 + 2] = (a.z + b4.z + c.z + d.z + e.z) * 0.2f;
            vals[i * 4 + 3] = (a.w + b4.w + c.w + d.w + e.w) * 0.2f;
        }
    }
    bf16x8 hv[4], lv[4];
#pragma unroll
    for (int e = 0; e < 32; e++) {
        float f = vals[e];
        unsigned hb = bf16_rne(f);
        float lof = f - __uint_as_float(hb << 16);
        hv[e >> 3][e & 7] = (short)hb;
        lv[e >> 3][e & 7] = (short)bf16_rne(lof);
    }
    int chunk0 = half * 128 + seg * 4;
#pragma unroll
    for (int c = 0; c < 4; c++) {
        size_t o = (size_t)(chunk0 + c) * nrows + rowg;
        dh[o] = hv[c];
        dl[o] = lv[c];
    }
}

// ---------------- merged: split-bf16 MFMA GEMM (blocks 0..624) + SYRK (625..754) ----
// Operands CHUNK-MAJOR [chunk][nrows]; wave loads are 1KB-contiguous.
__global__ __launch_bounds__(256) void gemm_syrk_kernel(const bf16x8* __restrict__ Ah,
                                                        const bf16x8* __restrict__ Al,
                                                        const bf16x8* __restrict__ Bh,
                                                        const bf16x8* __restrict__ Bl,
                                                        float* __restrict__ xy,
                                                        float* __restrict__ gxx,
                                                        float* __restrict__ gyy) {
    __shared__ bf16x8 sAh[512], sAl[512], sBh[512], sBl[512];  // 32 KB
    int tid = threadIdx.x, lane = tid & 63, wid = tid >> 6;
    int o = blockIdx.x;
    if (o >= GEMM_BLKS) {
        // ---- SYRK path: one wave per 32x32 Gram matrix ----
        int ww = (o - GEMM_BLKS) * 4 + wid;
        const bf16x8* hi;
        const bf16x8* lo;
        int nrows, row0;
        float* outp;
        if (ww < NQ) {
            hi = Ah; lo = Al; nrows = NQROWS; row0 = ww * 32;
            outp = gxx + (size_t)ww * (T * T);
        } else {
            hi = Bh; lo = Bl; nrows = NPROWS; row0 = (ww - NQ) * 32;
            outp = gyy + (size_t)(ww - NQ) * (T * T);
        }
        int r = lane & 15, g = lane >> 4;
        f32x4 acc[2][2];
        f32x4 zero = {0.f, 0.f, 0.f, 0.f};
        acc[0][0] = zero; acc[0][1] = zero; acc[1][0] = zero; acc[1][1] = zero;
        for (int t = 0; t < C / 32; t++) {
            size_t base = (size_t)(t * 4 + g) * nrows + row0 + r;
            bf16x8 h0 = hi[base], h1 = hi[base + 16];
            bf16x8 l0 = lo[base], l1 = lo[base + 16];
            acc[0][0] = __builtin_amdgcn_mfma_f32_16x16x32_bf16(h0, h0, acc[0][0], 0, 0, 0);
            acc[0][0] = __builtin_amdgcn_mfma_f32_16x16x32_bf16(h0, l0, acc[0][0], 0, 0, 0);
            acc[0][0] = __builtin_amdgcn_mfma_f32_16x16x32_bf16(l0, h0, acc[0][0], 0, 0, 0);
            acc[0][1] = __builtin_amdgcn_mfma_f32_16x16x32_bf16(h0, h1, acc[0][1], 0, 0, 0);
            acc[0][1] = __builtin_amdgcn_mfma_f32_16x16x32_bf16(h0, l1, acc[0][1], 0, 0, 0);
            acc[0][1] = __builtin_amdgcn_mfma_f32_16x16x32_bf16(l0, h1, acc[0][1], 0, 0, 0);
            acc[1][0] = __builtin_amdgcn_mfma_f32_16x16x32_bf16(h1, h0, acc[1][0], 0, 0, 0);
            acc[1][0] = __builtin_amdgcn_mfma_f32_16x16x32_bf16(h1, l0, acc[1][0], 0, 0, 0);
            acc[1][0] = __builtin_amdgcn_mfma_f32_16x16x32_bf16(l1, h0, acc[1][0], 0, 0, 0);
            acc[1][1] = __builtin_amdgcn_mfma_f32_16x16x32_bf16(h1, h1, acc[1][1], 0, 0, 0);
            acc[1][1] = __builtin_amdgcn_mfma_f32_16x16x32_bf16(h1, l1, acc[1][1], 0, 0, 0);
            acc[1][1] = __builtin_amdgcn_mfma_f32_16x16x32_bf16(l1, h1, acc[1][1], 0, 0, 0);
        }
#pragma unroll
        for (int mi = 0; mi < 2; mi++)
#pragma unroll
            for (int ni = 0; ni < 2; ni++)
#pragma unroll
                for (int j = 0; j < 4; j++)
                    outp[(mi * 16 + g * 4 + j) * T + ni * 16 + r] = acc[mi][ni][j];
        return;
    }
    // ---- GEMM path ----
    // bijective XCD swizzle over 625 = 8*78+1
    int xcd = o & 7, slot = o >> 3;
    int v = (xcd < 1 ? xcd * 79 : 79 + (xcd - 1) * 78) + slot;
    int bm = v / 5, bn = v % 5;
    int wr = wid >> 1, wc = wid & 1;
    int m0 = bm * 128, n0 = bn * 128;
    int i0 = tid, i1 = tid + 256;
    const bf16x8* gAh0 = Ah + (size_t)(i0 >> 7) * NQROWS + m0 + (i0 & 127);
    const bf16x8* gAh1 = Ah + (size_t)(i1 >> 7) * NQROWS + m0 + (i1 & 127);
    const bf16x8* gAl0 = Al + (size_t)(i0 >> 7) * NQROWS + m0 + (i0 & 127);
    const bf16x8* gAl1 = Al + (size_t)(i1 >> 7) * NQROWS + m0 + (i1 & 127);
    const bf16x8* gBh0 = Bh + (size_t)(i0 >> 7) * NPROWS + n0 + (i0 & 127);
    const bf16x8* gBh1 = Bh + (size_t)(i1 >> 7) * NPROWS + n0 + (i1 & 127);
    const bf16x8* gBl0 = Bl + (size_t)(i0 >> 7) * NPROWS + n0 + (i0 & 127);
    const bf16x8* gBl1 = Bl + (size_t)(i1 >> 7) * NPROWS + n0 + (i1 & 127);
    f32x4 acc[4][4];
    f32x4 zero = {0.f, 0.f, 0.f, 0.f};
#pragma unroll
    for (int mi = 0; mi < 4; mi++)
#pragma unroll
        for (int ni = 0; ni < 4; ni++) acc[mi][ni] = zero;
    int g = lane >> 4, r = lane & 15;
    int aoff = g * 128 + wr * 64 + r;
    int boff = g * 128 + wc * 64 + r;
    for (int t = 0; t < C / 32; t++) {
        gload16(gAh0, &sAh[i0]); gload16(gAh1, &sAh[i1]);
        gload16(gAl0, &sAl[i0]); gload16(gAl1, &sAl[i1]);
        gload16(gBh0, &sBh[i0]); gload16(gBh1, &sBh[i1]);
        gload16(gBl0, &sBl[i0]); gload16(gBl1, &sBl[i1]);
        gAh0 += 4 * NQROWS; gAh1 += 4 * NQROWS; gAl0 += 4 * NQROWS; gAl1 += 4 * NQROWS;
        gBh0 += 4 * NPROWS; gBh1 += 4 * NPROWS; gBl0 += 4 * NPROWS; gBl1 += 4 * NPROWS;
        __syncthreads();
        bf16x8 ah[4], al[4], bh[4], bl[4];
#pragma unroll
        for (int i = 0; i < 4; i++) {
            ah[i] = sAh[aoff + i * 16];
            al[i] = sAl[aoff + i * 16];
            bh[i] = sBh[boff + i * 16];
            bl[i] = sBl[boff + i * 16];
        }
#pragma unroll
        for (int mi = 0; mi < 4; mi++)
#pragma unroll
            for (int ni = 0; ni < 4; ni++) {
                acc[mi][ni] = __builtin_amdgcn_mfma_f32_16x16x32_bf16(ah[mi], bh[ni], acc[mi][ni], 0, 0, 0);
                acc[mi][ni] = __builtin_amdgcn_mfma_f32_16x16x32_bf16(ah[mi], bl[ni], acc[mi][ni], 0, 0, 0);
                acc[mi][ni] = __builtin_amdgcn_mfma_f32_16x16x32_bf16(al[mi], bh[ni], acc[mi][ni], 0, 0, 0);
            }
        __syncthreads();
    }
    int orow = m0 + wr * 64 + (lane >> 4) * 4;
    int ocol = n0 + wc * 64 + (lane & 15);
#pragma unroll
    for (int mi = 0; mi < 4; mi++)
#pragma unroll
        for (int ni = 0; ni < 4; ni++)
#pragma unroll
            for (int j = 0; j < 4; j++)
                xy[(size_t)(orow + mi * 16 + j) * NPROWS + ocol + ni * 16] = acc[mi][ni][j];
}

// ---------------- extract row norms from Gram diagonals ----------------
__global__ void diag_kernel(const float* __restrict__ gxx, const float* __restrict__ gyy,
                            float* __restrict__ x2, float* __restrict__ y2) {
    int i = blockIdx.x * 256 + threadIdx.x;
    if (i < NQROWS) {
        x2[i] = gxx[(size_t)(i >> 5) * (T * T) + (i & 31) * (T + 1)];
    } else if (i < NQROWS + NPROWS) {
        int j = i - NQROWS;
        y2[j] = gyy[(size_t)(j >> 5) * (T * T) + (j & 31) * (T + 1)];
    }
}

// ---------------- merged soft-DTW DP: one thread per 32x32 cost matrix ----------------
__global__ void softdtw_all_kernel(const float* __restrict__ xy, const float* __restrict__ gxx,
                                   const float* __restrict__ gyy, const float* __restrict__ x2,
                                   const float* __restrict__ y2, float* __restrict__ dxy,
                                   float* __restrict__ dxx, float* __restrict__ dyy) {
    int mm = blockIdx.x * 64 + threadIdx.x;
    if (mm >= NMM) return;
    const float* rterm;
    const float* cterm;
    const float* cptr;
    int cstride;
    float* outp;
    if (mm < NQ * NCLASS) {
        int q = mm / NCLASS, m = mm % NCLASS;
        rterm = x2 + q * T;
        cterm = y2 + m * T;
        cptr = xy + (size_t)(q * T) * NPROWS + m * T;
        cstride = NPROWS;
        outp = dxy + mm;
    } else if (mm < NQ * NCLASS + NQ) {
        int i = mm - NQ * NCLASS;
        rterm = x2 + i * T;
        cterm = rterm;
        cptr = gxx + (size_t)i * (T * T);
        cstride = T;
        outp = dxx + i;
    } else {
        int i = mm - NQ * NCLASS - NQ;
        rterm = y2 + i * T;
        cterm = rterm;
        cptr = gyy + (size_t)i * (T * T);
        cstride = T;
        outp = dyy + i;
    }
    float cj[T];
#pragma unroll
    for (int j = 0; j < T; j++) cj[j] = cterm[j];
    float Rp[T + 1];
    Rp[0] = 0.f;
#pragma unroll
    for (int j = 1; j <= T; j++) Rp[j] = BIG;
    for (int i = 0; i < T; i++) {
        float diag = Rp[0];
        Rp[0] = BIG;
        float left = BIG;
        float ai = rterm[i];
        const float4* crow4 = (const float4*)(cptr + (size_t)i * cstride);
        float cr[T];
#pragma unroll
        for (int jj = 0; jj < 8; jj++) {
            float4 v = crow4[jj];
            cr[jj * 4 + 0] = v.x; cr[jj * 4 + 1] = v.y;
            cr[jj * 4 + 2] = v.z; cr[jj * 4 + 3] = v.w;
        }
#pragma unroll
        for (int j = 0; j < T; j++) {
            float up = Rp[j + 1];
            float d = ai + cj[j] - 2.0f * cr[j];
            float mn = fminf(diag, fminf(up, left));
            float ssum = __expf((mn - diag) * INVG) + __expf((mn - up) * INVG) +
                         __expf((mn - left) * INVG);
            float rr = d + mn - GAMMA * __logf(ssum);
            diag = up;
            Rp[j + 1] = rr;
            left = rr;
        }
    }
    *outp = Rp[T];
}

// ---------------- finalize: dist, log-softmax, loss, acc ----------------
__global__ __launch_bounds__(512) void finalize_kernel(const float* __restrict__ dxy,
                                                       const float* __restrict__ dxx,
                                                       const float* __restrict__ dyy,
                                                       float* __restrict__ out) {
    __shared__ float sl[512];
    __shared__ float sa[512];
    int q = threadIdx.x;
    float bl = 0.f, fl = 0.f;
    if (q < NQ) {
        float dxxq = dxx[q];
        int cq = q / NQPC;
        float dd[NCLASS];
#pragma unroll
        for (int m = 0; m < NCLASS; m++)
            dd[m] = dxy[q * NCLASS + m] - 0.5f * (dxxq + dyy[m]);
        float best = dd[0];
        int bi = 0;
#pragma unroll
        for (int m = 1; m < NCLASS; m++) {
            if (dd[m] < best) { best = dd[m]; bi = m; }
        }
        float s = 0.f;
        float dcq = dd[0];
#pragma unroll
        for (int m = 0; m < NCLASS; m++) {
            s += __expf(best - dd[m]);
            if (m == cq) dcq = dd[m];
        }
        float lse = __logf(s) - best;
        bl = dcq + lse;
        out[2 + q] = bl;
        fl = (bi == cq) ? 1.f : 0.f;
    }
    sl[threadIdx.x] = bl;
    sa[threadIdx.x] = fl;
    __syncthreads();
    for (int off = 256; off; off >>= 1) {
        if (threadIdx.x < off) {
            sl[threadIdx.x] += sl[threadIdx.x + off];
            sa[threadIdx.x] += sa[threadIdx.x + off];
        }
        __syncthreads();
    }
    if (threadIdx.x == 0) {
        out[0] = sl[0] / (float)NQ;
        out[1] = sa[0] / (float)NQ;
    }
}

extern "C" void kernel_launch(void* const* d_in, const int* in_sizes, int n_in,
                              void* d_out, int out_size, void* d_ws, size_t ws_size,
                              hipStream_t stream) {
    const float* inp = (const float*)d_in[0];
    const int* target = (const int*)d_in[1];
    float* out = (float*)d_out;
    char* ws = (char*)d_ws;

    size_t off = 0;
    auto carve = [&](size_t bytes) {
        void* p = ws + off;
        off = (off + bytes + 255) & ~(size_t)255;
        return p;
    };
    int* order = (int*)carve(NTOT * sizeof(int));
    int* qsrc = (int*)carve(NQ * sizeof(int));
    float* x2 = (float*)carve((size_t)NQROWS * sizeof(float));
    float* y2 = (float*)carve((size_t)NPROWS * sizeof(float));
    float* xy = (float*)carve((size_t)NQROWS * NPROWS * sizeof(float));  // 41 MB
    float* gxx = (float*)carve((size_t)NQ * T * T * sizeof(float));
    float* gyy = (float*)carve((size_t)NCLASS * T * T * sizeof(float));
    float* dxy = (float*)carve((size_t)NQ * NCLASS * sizeof(float));
    float* dxx = (float*)carve((size_t)NQ * sizeof(float));
    float* dyy = (float*)carve((size_t)NCLASS * sizeof(float));
    bf16x8* Ah = (bf16x8*)carve((size_t)(C / 8) * NQROWS * 16);  // 65.5 MB chunk-major
    bf16x8* Al = (bf16x8*)carve((size_t)(C / 8) * NQROWS * 16);
    bf16x8* Bh = (bf16x8*)carve((size_t)(C / 8) * NPROWS * 16);  // 2.6 MB
    bf16x8* Bl = (bf16x8*)carve((size_t)(C / 8) * NPROWS * 16);
    (void)ws_size;

    sort_kernel<<<1, 640, 0, stream>>>(target, order, qsrc);
    stage_kernel<<<STAGE_BLKS_A + STAGE_BLKS_B, 512, 0, stream>>>(inp, qsrc, order, Ah, Al, Bh, Bl);
    gemm_syrk_kernel<<<GEMM_BLKS + SYRK_BLKS, 256, 0, stream>>>(Ah, Al, Bh, Bl, xy, gxx, gyy);
    diag_kernel<<<(NQROWS + NPROWS + 255) / 256, 256, 0, stream>>>(gxx, gyy, x2, y2);
    softdtw_all_kernel<<<(NMM + 63) / 64, 64, 0, stream>>>(xy, gxx, gyy, x2, y2, dxy, dxx, dyy);
    finalize_kernel<<<1, 512, 0, stream>>>(dxy, dxx, dyy, out);
}